// Round 5
// baseline (336.087 us; speedup 1.0000x reference)
//
#include <hip/hip_runtime.h>

#define N_NODES 50000
#define N_EDGES 800000
#define CAP 64
#define ROWS 16   // nodes per GEMM1 block; 50000 = 3125 * 16
#define ZR N_NODES   // zero-row index for padded bucket slots

typedef _Float16 f16;
typedef unsigned short u16;
typedef unsigned int u32;
typedef f16 f16x4 __attribute__((ext_vector_type(4)));

// ---------------- init: cnt=0, bucket=ZR-fill, zero rows, weight interleave ----------------
__global__ __launch_bounds__(256) void k_init(
        int* __restrict__ cnt, uint4* __restrict__ bucket4,
        const float* __restrict__ Wl2, const float* __restrict__ Wr2,
        const float* __restrict__ Wlm, const float* __restrict__ Wrm,
        const float* __restrict__ Wlv, const float* __restrict__ Wrv,
        float2* __restrict__ W2i, float2* __restrict__ W3i,
        u32* __restrict__ zr_t1l, u32* __restrict__ zr_t2l, u32* __restrict__ zr_p)
{
    int t = blockIdx.x * 256 + threadIdx.x;
    const u32 ZP = 0xC350C350u;                 // (50000<<16)|50000
    if (t < 400000) { bucket4[t] = make_uint4(ZP, ZP, ZP, ZP); return; }
    t -= 400000;
    if (t < N_NODES) { cnt[t] = 0; return; }
    t -= N_NODES;
    if (t < 117 * 42) { W2i[t] = make_float2(Wl2[t], Wr2[t]); return; }
    t -= 117 * 42;
    if (t < 42 * 48) {
        int k = t / 48, j = t - k * 48;
        int o = (j < 24) ? j : j - 24;
        const float* L = (j < 24) ? Wlm : Wlv;
        const float* R = (j < 24) ? Wrm : Wrv;
        W3i[t] = make_float2(L[k * 24 + o], R[k * 24 + o]);
        return;
    }
    t -= 42 * 48;
    if (t < 64) { zr_t1l[t] = 0; return; }      // t1l ZR row: 256B
    t -= 64;
    if (t < 22) { zr_t2l[t] = 0; return; }      // t2l ZR row: 88B
    t -= 22;
    if (t < 24) { zr_p[t] = 0; return; }        // p ZR row: 96B
}

// ---------------- build: bucket edges by dst (ushort src ids; pad slots stay ZR) ----------------
__global__ void k_build(const int* __restrict__ ei, int* __restrict__ cnt,
                        u16* __restrict__ bucket) {
    int e = blockIdx.x * blockDim.x + threadIdx.x;
    if (e >= N_EDGES) return;
    int s = ei[e];
    int d = ei[N_EDGES + e];
    int pos = atomicAdd(&cnt[d], 1);
    if (pos < CAP) bucket[d * CAP + pos] = (u16)s;
}

// ------- t1l = x@Wl1 (f16, stride 128, cols 117..127 zeroed)
// ------- t1r = x@Wr1 + b1 (fp32, stride 120, cols 117..119 zeroed) -------
__global__ __launch_bounds__(256) void k_gemm1(const float* __restrict__ x,
                        const float* __restrict__ Wl, const float* __restrict__ Wr,
                        const float* __restrict__ b1,
                        f16* __restrict__ t1l, float* __restrict__ t1r) {
    int base = blockIdx.x * ROWS;
    int t = threadIdx.x;
    __shared__ __align__(16) float xs[128][20];
    for (int idx = t; idx < ROWS * 128; idx += 256) {
        int r = idx >> 7, c = idx & 127;
        xs[c][r] = x[(size_t)base * 128 + idx];
    }
    __syncthreads();
    if (t < 234) {
        const float* Wc = (t < 117) ? (Wl + t) : (Wr + (t - 117));
        float acc[ROWS];
#pragma unroll
        for (int r = 0; r < ROWS; ++r) acc[r] = 0.f;
#pragma unroll 4
        for (int k = 0; k < 128; ++k) {
            float w = Wc[(size_t)k * 117];
            const float4* xv = (const float4*)&xs[k][0];
            float4 x0 = xv[0], x1 = xv[1], x2 = xv[2], x3 = xv[3];
            acc[0]  = fmaf(x0.x, w, acc[0]);  acc[1]  = fmaf(x0.y, w, acc[1]);
            acc[2]  = fmaf(x0.z, w, acc[2]);  acc[3]  = fmaf(x0.w, w, acc[3]);
            acc[4]  = fmaf(x1.x, w, acc[4]);  acc[5]  = fmaf(x1.y, w, acc[5]);
            acc[6]  = fmaf(x1.z, w, acc[6]);  acc[7]  = fmaf(x1.w, w, acc[7]);
            acc[8]  = fmaf(x2.x, w, acc[8]);  acc[9]  = fmaf(x2.y, w, acc[9]);
            acc[10] = fmaf(x2.z, w, acc[10]); acc[11] = fmaf(x2.w, w, acc[11]);
            acc[12] = fmaf(x3.x, w, acc[12]); acc[13] = fmaf(x3.y, w, acc[13]);
            acc[14] = fmaf(x3.z, w, acc[14]); acc[15] = fmaf(x3.w, w, acc[15]);
        }
        if (t < 117) {
#pragma unroll
            for (int r = 0; r < ROWS; ++r)
                t1l[(size_t)(base + r) * 128 + t] = (f16)acc[r];
        } else {
            int col = t - 117;
            float bb = b1[col];
#pragma unroll
            for (int r = 0; r < ROWS; ++r)
                t1r[(size_t)(base + r) * 120 + col] = acc[r] + bb;
        }
    } else if (t < 245) {
        int c = 117 + (t - 234);
#pragma unroll
        for (int r = 0; r < ROWS; ++r) t1l[(size_t)(base + r) * 128 + c] = (f16)0.f;
    } else if (t < 248) {
        int c = 117 + (t - 245);
#pragma unroll
        for (int r = 0; r < ROWS; ++r) t1r[(size_t)(base + r) * 120 + c] = 0.f;
    }
}

// ---- fused1: 4 waves/block, 2 nodes/wave. h1 = relu(gather(t1l)/deg + t1r);
// ----         t2l = h1@Wl2 (f16, 44 cols), s2 = h1@Wr2 + b2 (44 cols). grid = 6250
__global__ __launch_bounds__(256, 8) void k_fused1(
        const f16* __restrict__ t1l, const float* __restrict__ t1r,
        const int* __restrict__ cnt, const u16* __restrict__ bucket,
        const float2* __restrict__ W2i, const float* __restrict__ b2,
        f16* __restrict__ t2l, float* __restrict__ s2)
{
    __shared__ __align__(16) float h1[8][120];
    __shared__ u32 sbo[4][2][64];
    int tid = threadIdx.x, w = tid >> 6, lane = tid & 63;
    int iA = (blockIdx.x * 4 + w) * 2, iB = iA + 1;
    int cA = cnt[iA], cB = cnt[iB];
    int nA = cA < CAP ? cA : CAP, nB = cB < CAP ? cB : CAP;
    sbo[w][0][lane] = (u32)bucket[(size_t)iA * CAP + lane] << 8;   // byte off, stride 256
    sbo[w][1][lane] = (u32)bucket[(size_t)iB * CAP + lane] << 8;
    int g = lane >= 30 ? 1 : 0;
    int d = lane - 30 * g;
    int dd = d < 30 ? d : 29;
    float deg = fmaxf((float)(g ? cB : cA), 1.f);
    int nmax = nA > nB ? nA : nB;
    const u32* so = &sbo[w][g][0];
    u32 lo = (u32)dd * 8u;
    const char* bp = (const char*)t1l;
    float ac0[4] = {0,0,0,0}, ac1[4] = {0,0,0,0};
    __builtin_amdgcn_wave_barrier();
    for (int e0 = 0; e0 < nmax; e0 += 8) {
        u32 ro[8];
#pragma unroll
        for (int u = 0; u < 8; ++u) ro[u] = so[e0 + u];
        f16x4 v[8];
#pragma unroll
        for (int u = 0; u < 8; ++u) v[u] = *(const f16x4*)(bp + (ro[u] + lo));
#pragma unroll
        for (int u = 0; u < 8; ++u) {
            float* a = (u & 1) ? ac1 : ac0;
            a[0] = fmaf((float)v[u].x, 1.0f, a[0]);
            a[1] = fmaf((float)v[u].y, 1.0f, a[1]);
            a[2] = fmaf((float)v[u].z, 1.0f, a[2]);
            a[3] = fmaf((float)v[u].w, 1.0f, a[3]);
        }
    }
    if (lane < 60) {
        float4 s = *(const float4*)(t1r + (size_t)(g ? iB : iA) * 120 + 4 * dd);
        float4 hv;
        hv.x = fmaxf((ac0[0] + ac1[0]) / deg + s.x, 0.f);
        hv.y = fmaxf((ac0[1] + ac1[1]) / deg + s.y, 0.f);
        hv.z = fmaxf((ac0[2] + ac1[2]) / deg + s.z, 0.f);
        hv.w = fmaxf((ac0[3] + ac1[3]) / deg + s.w, 0.f);
        *(float4*)&h1[w * 2 + g][4 * dd] = hv;
    }
    __builtin_amdgcn_wave_barrier();
    int j = lane;
    if (j < 44) {
        float pA = 0.f, pB = 0.f, qA = 0.f, qB = 0.f;
        if (j < 42) {
            const float4* hA = (const float4*)&h1[w * 2][0];
            const float4* hB = (const float4*)&h1[w * 2 + 1][0];
            const float2* Wj = W2i + j;
#pragma unroll 2
            for (int kk = 0; kk < 29; ++kk) {      // k = 0..115
                float4 a = hA[kk], b = hB[kk];
                float av[4] = {a.x, a.y, a.z, a.w};
                float bv[4] = {b.x, b.y, b.z, b.w};
#pragma unroll
                for (int u = 0; u < 4; ++u) {
                    float2 wlr = Wj[(size_t)(4 * kk + u) * 42];
                    pA = fmaf(av[u], wlr.x, pA); qA = fmaf(av[u], wlr.y, qA);
                    pB = fmaf(bv[u], wlr.x, pB); qB = fmaf(bv[u], wlr.y, qB);
                }
            }
            float2 wlr = Wj[(size_t)116 * 42];     // k = 116 tail
            float va = h1[w * 2][116], vb = h1[w * 2 + 1][116];
            pA = fmaf(va, wlr.x, pA); qA = fmaf(va, wlr.y, qA);
            pB = fmaf(vb, wlr.x, pB); qB = fmaf(vb, wlr.y, qB);
            float bb = b2[j];
            qA += bb; qB += bb;
        }
        t2l[(size_t)iA * 44 + j] = (f16)pA;        // j=42,43 write zero pads
        t2l[(size_t)iB * 44 + j] = (f16)pB;
        s2[(size_t)iA * 44 + j] = qA;
        s2[(size_t)iB * 44 + j] = qB;
    }
}

// ---- fused2: 4 waves/block, 5 nodes/wave. h2 = relu(gather(t2l)/deg + s2);
// ----         p = h2@[Wlm|Wlv] (f16, 48 cols), out self = h2@[Wrm|Wrv] + b. grid = 2500
__global__ __launch_bounds__(256, 8) void k_fused2(
        const f16* __restrict__ t2l, const float* __restrict__ s2,
        const int* __restrict__ cnt, const u16* __restrict__ bucket,
        const float2* __restrict__ W3i, const float* __restrict__ bm,
        const float* __restrict__ bv,
        f16* __restrict__ p, float* __restrict__ out)
{
    __shared__ __align__(16) float h2[20][48];
    __shared__ u32 sbo[4][5][64];
    int tid = threadIdx.x, w = tid >> 6, lane = tid & 63;
    int i0 = (blockIdx.x * 4 + w) * 5;
    int c[5], n[5];
#pragma unroll
    for (int q = 0; q < 5; ++q) {
        c[q] = cnt[i0 + q];
        n[q] = c[q] < CAP ? c[q] : CAP;
        sbo[w][q][lane] = (u32)bucket[(size_t)(i0 + q) * CAP + lane] * 88u;
    }
    int nmax = n[0];
#pragma unroll
    for (int q = 1; q < 5; ++q) nmax = n[q] > nmax ? n[q] : nmax;
    int g = lane / 11; if (g > 4) g = 4;
    int d = lane - 11 * g;
    int dd = d < 11 ? d : 10;
    bool act = lane < 55;
    float deg = fmaxf((float)c[g], 1.f);
    const u32* so = &sbo[w][g][0];
    u32 lo = (u32)dd * 8u;
    const char* bp = (const char*)t2l;
    float ac0[4] = {0,0,0,0}, ac1[4] = {0,0,0,0};
    __builtin_amdgcn_wave_barrier();
    for (int e0 = 0; e0 < nmax; e0 += 8) {
        u32 ro[8];
#pragma unroll
        for (int u = 0; u < 8; ++u) ro[u] = so[e0 + u];
        f16x4 v[8];
#pragma unroll
        for (int u = 0; u < 8; ++u) v[u] = *(const f16x4*)(bp + (ro[u] + lo));
#pragma unroll
        for (int u = 0; u < 8; ++u) {
            float* a = (u & 1) ? ac1 : ac0;
            a[0] = fmaf((float)v[u].x, 1.0f, a[0]);
            a[1] = fmaf((float)v[u].y, 1.0f, a[1]);
            a[2] = fmaf((float)v[u].z, 1.0f, a[2]);
            a[3] = fmaf((float)v[u].w, 1.0f, a[3]);
        }
    }
    if (act) {
        float4 s = *(const float4*)(s2 + (size_t)(i0 + g) * 44 + 4 * dd);
        float4 hv;
        hv.x = fmaxf((ac0[0] + ac1[0]) / deg + s.x, 0.f);
        hv.y = fmaxf((ac0[1] + ac1[1]) / deg + s.y, 0.f);
        hv.z = fmaxf((ac0[2] + ac1[2]) / deg + s.z, 0.f);
        hv.w = fmaxf((ac0[3] + ac1[3]) / deg + s.w, 0.f);
        *(float4*)&h2[w * 5 + g][4 * dd] = hv;     // cols 0..43 (42,43 are zeros)
    }
    __builtin_amdgcn_wave_barrier();
    int j = lane;
    if (j < 48) {
        int o = (j < 24) ? j : j - 24;
        float bias = (j < 24) ? bm[o] : bv[o];
        float pq[5], qq[5];
#pragma unroll
        for (int q = 0; q < 5; ++q) { pq[q] = 0.f; qq[q] = 0.f; }
        const float2* Wj = W3i + j;
        for (int kk = 0; kk < 10; ++kk) {          // k = 0..39
            float4 hq[5];
#pragma unroll
            for (int q = 0; q < 5; ++q) hq[q] = *(const float4*)&h2[w * 5 + q][4 * kk];
#pragma unroll
            for (int u = 0; u < 4; ++u) {
                float2 wlr = Wj[(size_t)(4 * kk + u) * 48];
#pragma unroll
                for (int q = 0; q < 5; ++q) {
                    float hv = ((const float*)&hq[q])[u];
                    pq[q] = fmaf(hv, wlr.x, pq[q]);
                    qq[q] = fmaf(hv, wlr.y, qq[q]);
                }
            }
        }
        for (int k = 40; k < 42; ++k) {
            float2 wlr = Wj[(size_t)k * 48];
#pragma unroll
            for (int q = 0; q < 5; ++q) {
                float hv = h2[w * 5 + q][k];
                pq[q] = fmaf(hv, wlr.x, pq[q]);
                qq[q] = fmaf(hv, wlr.y, qq[q]);
            }
        }
        size_t half = (j < 24) ? 0 : (size_t)N_NODES * 24;
#pragma unroll
        for (int q = 0; q < 5; ++q) {
            p[(size_t)(i0 + q) * 48 + j] = (f16)pq[q];
            out[half + (size_t)(i0 + q) * 24 + o] = qq[q] + bias;
        }
    }
}

// ---- final: 4 waves/block, 5 nodes/wave; mean-gather p, float4-RMW into out. grid = 2500
__global__ __launch_bounds__(256, 8) void k_final(
        const f16* __restrict__ p, const int* __restrict__ cnt,
        const u16* __restrict__ bucket, float* __restrict__ out)
{
    __shared__ u32 sbo[4][5][64];
    int tid = threadIdx.x, w = tid >> 6, lane = tid & 63;
    int i0 = (blockIdx.x * 4 + w) * 5;
    int c[5], n[5];
#pragma unroll
    for (int q = 0; q < 5; ++q) {
        c[q] = cnt[i0 + q];
        n[q] = c[q] < CAP ? c[q] : CAP;
        sbo[w][q][lane] = (u32)bucket[(size_t)(i0 + q) * CAP + lane] * 96u;
    }
    int nmax = n[0];
#pragma unroll
    for (int q = 1; q < 5; ++q) nmax = n[q] > nmax ? n[q] : nmax;
    int g = lane / 12; if (g > 4) g = 4;
    int d = lane - 12 * g;
    int dd = d < 12 ? d : 11;
    bool act = lane < 60;
    float deg = fmaxf((float)c[g], 1.f);
    const u32* so = &sbo[w][g][0];
    u32 lo = (u32)dd * 8u;
    const char* bp = (const char*)p;
    float ac0[4] = {0,0,0,0}, ac1[4] = {0,0,0,0};
    __builtin_amdgcn_wave_barrier();
    for (int e0 = 0; e0 < nmax; e0 += 8) {
        u32 ro[8];
#pragma unroll
        for (int u = 0; u < 8; ++u) ro[u] = so[e0 + u];
        f16x4 v[8];
#pragma unroll
        for (int u = 0; u < 8; ++u) v[u] = *(const f16x4*)(bp + (ro[u] + lo));
#pragma unroll
        for (int u = 0; u < 8; ++u) {
            float* a = (u & 1) ? ac1 : ac0;
            a[0] = fmaf((float)v[u].x, 1.0f, a[0]);
            a[1] = fmaf((float)v[u].y, 1.0f, a[1]);
            a[2] = fmaf((float)v[u].z, 1.0f, a[2]);
            a[3] = fmaf((float)v[u].w, 1.0f, a[3]);
        }
    }
    if (act) {
        int i_my = i0 + g;
        size_t addr = (dd < 6) ? ((size_t)i_my * 24 + 4 * dd)
                               : ((size_t)N_NODES * 24 + (size_t)i_my * 24 + 4 * (dd - 6));
        float4 o4 = *(const float4*)(out + addr);
        o4.x += (ac0[0] + ac1[0]) / deg;
        o4.y += (ac0[1] + ac1[1]) / deg;
        o4.z += (ac0[2] + ac1[2]) / deg;
        o4.w += (ac0[3] + ac1[3]) / deg;
        *(float4*)(out + addr) = o4;
    }
}

extern "C" void kernel_launch(void* const* d_in, const int* in_sizes, int n_in,
                              void* d_out, int out_size, void* d_ws, size_t ws_size,
                              hipStream_t stream) {
    const float* x   = (const float*)d_in[0];
    const int*   ei  = (const int*)d_in[1];
    const float* Wl1 = (const float*)d_in[2];
    const float* Wr1 = (const float*)d_in[3];
    const float* b1  = (const float*)d_in[4];
    const float* Wl2 = (const float*)d_in[5];
    const float* Wr2 = (const float*)d_in[6];
    const float* b2  = (const float*)d_in[7];
    const float* Wlm = (const float*)d_in[8];
    const float* Wrm = (const float*)d_in[9];
    const float* bm  = (const float*)d_in[10];
    const float* Wlv = (const float*)d_in[11];
    const float* Wrv = (const float*)d_in[12];
    const float* bv  = (const float*)d_in[13];
    float* out = (float*)d_out;

    // workspace layout (bytes):
    //   cnt    @ 0          : 200,000  (pad 204,800)
    //   bucket @ 204,800    : 50000*64*2       = 6,400,000  -> 6,604,800
    //   t1l    @ 6,604,800  : 50001*128*2      = 12,800,256 -> 19,405,056
    //   t1r    @ 19,405,056 : 50000*120*4      = 24,000,000 -> 43,405,056
    //   t2l    @ 43,405,056 : 50001*44*2       = 4,400,088  -> 47,805,144
    //   s2     @ 47,805,152 : 50000*44*4       = 8,800,000  -> 56,605,152
    //   p      @ 56,605,152 : 50001*48*2       = 4,800,096  -> 61,405,248
    //   W2i    @ 61,405,248 : 117*42*8         = 39,312     -> 61,444,560
    //   W3i    @ 61,444,560 : 42*48*8          = 16,128     -> 61,460,688
    char* ws = (char*)d_ws;
    int*    cnt    = (int*)(ws);
    u16*    bucket = (u16*)(ws + 204800);
    f16*    t1l    = (f16*)(ws + 6604800);
    float*  t1r    = (float*)(ws + 19405056);
    f16*    t2l    = (f16*)(ws + 43405056);
    float*  s2     = (float*)(ws + 47805152);
    f16*    p      = (f16*)(ws + 56605152);
    float2* W2i    = (float2*)(ws + 61405248);
    float2* W3i    = (float2*)(ws + 61444560);
    u32* zr_t1l = (u32*)(t1l + (size_t)ZR * 128);
    u32* zr_t2l = (u32*)(t2l + (size_t)ZR * 44);
    u32* zr_p   = (u32*)(p   + (size_t)ZR * 48);

    // k_init thread count: 400000 + 50000 + 4914 + 2016 + 64 + 22 + 24 = 457,040
    k_init<<<1786, 256, 0, stream>>>(cnt, (uint4*)bucket, Wl2, Wr2, Wlm, Wrm, Wlv, Wrv,
                                     W2i, W3i, zr_t1l, zr_t2l, zr_p);
    k_build<<<(N_EDGES + 255) / 256, 256, 0, stream>>>(ei, cnt, bucket);
    k_gemm1<<<N_NODES / ROWS, 256, 0, stream>>>(x, Wl1, Wr1, b1, t1l, t1r);
    k_fused1<<<N_NODES / 8, 256, 0, stream>>>(t1l, t1r, cnt, bucket, W2i, b2, t2l, s2);
    k_fused2<<<N_NODES / 20, 256, 0, stream>>>(t2l, s2, cnt, bucket, W3i, bm, bv, p, out);
    k_final<<<N_NODES / 20, 256, 0, stream>>>(p, cnt, bucket, out);
}